// Round 3
// baseline (604.435 us; speedup 1.0000x reference)
//
#include <hip/hip_runtime.h>
#include <hip/hip_bf16.h>

// Problem constants
#define L_SEQ   16384
#define D_IO    2048
#define HEADS   16
#define DHEAD   128
#define KDIM    2048
#define KT      (KDIM / 32)   // 64 K-tiles of BK=32

typedef __attribute__((ext_vector_type(8))) short short8;
typedef __attribute__((ext_vector_type(16))) float floatx16;

typedef const __attribute__((address_space(1))) unsigned int gu_t;
typedef __attribute__((address_space(3))) unsigned int lu_t;

__device__ __forceinline__ unsigned short f2bf(float f) {
  unsigned u = __float_as_uint(f);
  u += 0x7fffu + ((u >> 16) & 1u);   // RNE
  return (unsigned short)(u >> 16);
}
__device__ __forceinline__ float bf2f(unsigned short s) {
  return __uint_as_float(((unsigned)s) << 16);
}

// ---------------- f32 -> bf16 convert (vectorized, grid-stride) ----------------
__global__ __launch_bounds__(256)
void cvt_f32_bf16(const float* __restrict__ x, unsigned short* __restrict__ y, long n)
{
  for (long i = ((long)blockIdx.x * 256 + threadIdx.x) * 8; i < n;
       i += (long)gridDim.x * 256 * 8) {
    const float4 v0 = *(const float4*)(x + i);
    const float4 v1 = *(const float4*)(x + i + 4);
    uint4 r;
    r.x = (unsigned)f2bf(v0.x) | ((unsigned)f2bf(v0.y) << 16);
    r.y = (unsigned)f2bf(v0.z) | ((unsigned)f2bf(v0.w) << 16);
    r.z = (unsigned)f2bf(v1.x) | ((unsigned)f2bf(v1.y) << 16);
    r.w = (unsigned)f2bf(v1.z) | ((unsigned)f2bf(v1.w) << 16);
    *(uint4*)(y + i) = r;
  }
}

// ------------- transpose + convert: S[2048][2048] f32 -> D[2048][2048] bf16 (D = S^T) -------------
__global__ __launch_bounds__(256)
void transpose_cvt(const float* __restrict__ S, unsigned short* __restrict__ D)
{
  __shared__ float tile[32][33];
  const int bn = blockIdx.x * 32;
  const int bk = blockIdx.y * 32;
  const int tx = threadIdx.x, ty = threadIdx.y;  // (32, 8)
  #pragma unroll
  for (int i = 0; i < 32; i += 8)
    tile[ty + i][tx] = S[(size_t)(bk + ty + i) * D_IO + bn + tx];
  __syncthreads();
  #pragma unroll
  for (int i = 0; i < 32; i += 8)
    D[(size_t)(bn + ty + i) * D_IO + bk + tx] = f2bf(tile[tx][ty + i]);
}

// =====================================================================
// 256x256-tile bf16 GEMM, BK=32, 8 waves (2Mx4N), 4-deep LDS pipeline,
// counted vmcnt(8), ONE barrier-pair per K-tile, 32x32x16 MFMA,
// T2 slot-XOR swizzle, T5 setprio, T1 XCD block swizzle.
// A: [M][2048] bf16 row-major. B: [N][2048] bf16 row-major (= B^T of math GEMM).
// C = A * B^T. EPI=0: bf16 out, EPI=1: f32 out + bias.
// =====================================================================
template<int EPI>
__global__ __launch_bounds__(512, 2)
void gemm256(const unsigned short* __restrict__ A,
             const unsigned short* __restrict__ B,
             void* __restrict__ Cout,
             const float* __restrict__ bias,
             const int ldc, const int bnShift)
{
  // 4 buffers x (A [256][32] 16KB | B [256][32] 16KB) = 128 KB
  __shared__ unsigned short lds[65536];

  const int t = threadIdx.x, lane = t & 63, wave = t >> 6;
  const int wm = wave >> 2, wn = wave & 3;       // 2 x 4 wave grid; per-wave out 128x64

  // T1: XCD-aware block swizzle (nwg % 8 == 0 for both GEMMs)
  const int nwg  = (int)(gridDim.x * gridDim.y);
  const int flat = (int)(blockIdx.y * gridDim.x + blockIdx.x);
  const int cpx  = nwg >> 3;
  const int swz  = (flat & 7) * cpx + (flat >> 3);
  const int bn = swz & ((1 << bnShift) - 1);
  const int bm = swz >> bnShift;

  // 32x32x16 fragment addressing: lane -> row rw=lane&31, k-half kh=lane>>5
  const int rw = lane & 31, kh = lane >> 5;
  const int rb = (lane >> 1) & 3;                 // swizzle bits = row bits 1..2
  // row K-width = 32 elems = 4 slots of 16B; slot(ks) = ks*2 + kh, swizzled by ^rb
  const int slot0 = ((kh ^ rb) << 3);             // shorts
  const int slot1 = (((2 + kh) ^ rb) << 3);       // shorts

  // staging: per call 512thr x 16B = 128 rows; row = t>>2
  // inverse swizzle on SOURCE: src k-slot = (t&3) ^ ((row>>1)&3) = (t&3)^((t>>3)&3)
  const int srow  = t >> 2;
  const int sslot = (((t & 3) ^ ((t >> 3) & 3)) * 8);      // elems
  const unsigned short* aSrc = A + (size_t)(bm * 256 + srow) * KDIM + sslot;
  const unsigned short* bSrc = B + (size_t)(bn * 256 + srow) * KDIM + sslot;

  floatx16 acc[4][2];
  #pragma unroll
  for (int mi = 0; mi < 4; ++mi)
    #pragma unroll
    for (int ni = 0; ni < 2; ++ni) acc[mi][ni] = (floatx16)0.f;

  // dest: wave-uniform base + lane*16 (linear); src: per-lane (pre-swizzled)
#define STAGE_A(tile, ts) do { const int _b = (tile) & 3;                                   \
    __builtin_amdgcn_global_load_lds((gu_t*)(aSrc + (size_t)(ts) * 32),                     \
                                     (lu_t*)(lds + _b * 16384 + wave * 512), 16, 0, 0);     \
    __builtin_amdgcn_global_load_lds((gu_t*)(aSrc + (size_t)128 * KDIM + (size_t)(ts) * 32),\
                                     (lu_t*)(lds + _b * 16384 + 4096 + wave * 512), 16, 0, 0); } while (0)
#define STAGE_B(tile, ts) do { const int _b = (tile) & 3;                                   \
    __builtin_amdgcn_global_load_lds((gu_t*)(bSrc + (size_t)(ts) * 32),                     \
                                     (lu_t*)(lds + _b * 16384 + 8192 + wave * 512), 16, 0, 0); \
    __builtin_amdgcn_global_load_lds((gu_t*)(bSrc + (size_t)128 * KDIM + (size_t)(ts) * 32),\
                                     (lu_t*)(lds + _b * 16384 + 12288 + wave * 512), 16, 0, 0); } while (0)

  // prologue: stage tiles 0,1,2
  STAGE_A(0, 0); STAGE_B(0, 0);
  STAGE_A(1, 1); STAGE_B(1, 1);
  STAGE_A(2, 2); STAGE_B(2, 2);
  asm volatile("s_waitcnt vmcnt(8)" ::: "memory");   // tile 0 landed; tiles 1,2 in flight
  __builtin_amdgcn_s_barrier();

  for (int tt = 0; tt < KT; ++tt) {
    const int b = tt & 3;
    const int ts = (tt + 3 < KT) ? (tt + 3) : (KT - 1);  // tail: harmless dup re-stage
    const unsigned short* As = lds + b * 16384;
    const unsigned short* Bs = As + 8192;

    short8 a0[4], a1[4], b0[2], b1[2];
    #pragma unroll
    for (int mi = 0; mi < 4; ++mi) {
      const unsigned short* p = As + (wm * 128 + mi * 32 + rw) * 32;
      a0[mi] = *(const short8*)(p + slot0);
      a1[mi] = *(const short8*)(p + slot1);
    }
    #pragma unroll
    for (int ni = 0; ni < 2; ++ni) {
      const unsigned short* p = Bs + (wn * 64 + ni * 32 + rw) * 32;
      b0[ni] = *(const short8*)(p + slot0);
      b1[ni] = *(const short8*)(p + slot1);
    }

    STAGE_A(tt + 3, ts);
    STAGE_B(tt + 3, ts);
    // tile tt+1 guaranteed landed; tiles tt+2, tt+3 (8 loads) stay in flight
    asm volatile("s_waitcnt vmcnt(8)" ::: "memory");
    __builtin_amdgcn_s_barrier();
    asm volatile("s_waitcnt lgkmcnt(0)" ::: "memory");
    __builtin_amdgcn_sched_barrier(0);
    __builtin_amdgcn_s_setprio(1);
    #pragma unroll
    for (int mi = 0; mi < 4; ++mi)
      #pragma unroll
      for (int ni = 0; ni < 2; ++ni)
        acc[mi][ni] = __builtin_amdgcn_mfma_f32_32x32x16_bf16(a0[mi], b0[ni], acc[mi][ni], 0, 0, 0);
    #pragma unroll
    for (int mi = 0; mi < 4; ++mi)
      #pragma unroll
      for (int ni = 0; ni < 2; ++ni)
        acc[mi][ni] = __builtin_amdgcn_mfma_f32_32x32x16_bf16(a1[mi], b1[ni], acc[mi][ni], 0, 0, 0);
    __builtin_amdgcn_s_setprio(0);
    __builtin_amdgcn_s_barrier();
  }
#undef STAGE_A
#undef STAGE_B

  // epilogue: 32x32 C/D layout col = lane&31, row = (reg&3) + 8*(reg>>2) + 4*(lane>>5)
  const int crow0 = bm * 256 + wm * 128 + kh * 4;
  const int ccol0 = bn * 256 + wn * 64 + rw;
  if (EPI == 0) {
    unsigned short* C = (unsigned short*)Cout;
    #pragma unroll
    for (int mi = 0; mi < 4; ++mi)
      #pragma unroll
      for (int ni = 0; ni < 2; ++ni) {
        const floatx16 v = acc[mi][ni];
        #pragma unroll
        for (int r = 0; r < 16; ++r)
          C[(size_t)(crow0 + mi * 32 + (r & 3) + ((r >> 2) << 3)) * ldc + ccol0 + ni * 32] = f2bf(v[r]);
      }
  } else {
    float* C = (float*)Cout;
    #pragma unroll
    for (int ni = 0; ni < 2; ++ni) {
      const float bv_ = bias[ccol0 + ni * 32];
      #pragma unroll
      for (int mi = 0; mi < 4; ++mi) {
        const floatx16 v = acc[mi][ni];
        #pragma unroll
        for (int r = 0; r < 16; ++r)
          C[(size_t)(crow0 + mi * 32 + (r & 3) + ((r >> 2) << 3)) * ldc + ccol0 + ni * 32] = v[r] + bv_;
      }
    }
  }
}

// ---------------- sliding-window attention pool ----------------
__global__ __launch_bounds__(256)
void winpool(const unsigned short* __restrict__ KV,
             const float* __restrict__ Q,
             unsigned short* __restrict__ P)
{
  const int lane = threadIdx.x & 63, wid = threadIdx.x >> 6;
  // XCD-chunked swizzle on t-blocks: window re-reads hit same-XCD L2
  const int bx = ((int)blockIdx.x & 7) * ((int)gridDim.x >> 3) + ((int)blockIdx.x >> 3);
  const int t = bx * 4 + wid;
  const int h = blockIdx.y;
  const float qx = Q[h * DHEAD + lane * 2];
  const float qy = Q[h * DHEAD + lane * 2 + 1];
  const float scale = 0.08838834764831845f;  // 1/sqrt(128)

  float s[4];
  #pragma unroll
  for (int w = 0; w < 4; ++w) {
    const int idx = t - 3 + w;
    float part = 0.f;
    if (idx >= 0) {
      const unsigned kk = *(const unsigned*)(KV + (size_t)idx * 4096 + h * DHEAD + lane * 2);
      part = qx * bf2f((unsigned short)(kk & 0xffffu)) +
             qy * bf2f((unsigned short)(kk >> 16));
    }
    #pragma unroll
    for (int off = 32; off > 0; off >>= 1) part += __shfl_xor(part, off);
    s[w] = part * scale;
  }
  float mx = -3.0e38f;
  #pragma unroll
  for (int w = 0; w < 4; ++w) if (t - 3 + w >= 0) mx = fmaxf(mx, s[w]);
  float p[4], sum = 0.f;
  #pragma unroll
  for (int w = 0; w < 4; ++w) {
    p[w] = (t - 3 + w >= 0) ? expf(s[w] - mx) : 0.f;
    sum += p[w];
  }
  const float inv = 1.f / sum;

  float o0 = 0.f, o1 = 0.f;
  #pragma unroll
  for (int w = 0; w < 4; ++w) {
    const int idx = t - 3 + w;
    if (idx >= 0) {
      const unsigned vv = *(const unsigned*)(KV + (size_t)idx * 4096 + 2048 + h * DHEAD + lane * 2);
      o0 += p[w] * bf2f((unsigned short)(vv & 0xffffu));
      o1 += p[w] * bf2f((unsigned short)(vv >> 16));
    }
  }
  o0 *= inv; o1 *= inv;
  const unsigned outw = ((unsigned)f2bf(o1) << 16) | (unsigned)f2bf(o0);
  *(unsigned*)(P + (size_t)t * D_IO + h * DHEAD + lane * 2) = outw;
}

// ---------------- launch ----------------
extern "C" void kernel_launch(void* const* d_in, const int* in_sizes, int n_in,
                              void* d_out, int out_size, void* d_ws, size_t ws_size,
                              hipStream_t stream)
{
  const float* e_seq = (const float*)d_in[0];
  const float* q     = (const float*)d_in[1];
  const float* Wk    = (const float*)d_in[2];
  const float* Wv    = (const float*)d_in[3];
  const float* Wo    = (const float*)d_in[4];
  const float* bo    = (const float*)d_in[5];
  float* out = (float*)d_out;

  char* ws = (char*)d_ws;
  unsigned short* Ebf  = (unsigned short*)ws;                                     // 64 MB (E bf16; reused as pooled)
  unsigned short* KV   = (unsigned short*)(ws + 67108864);                        // 128 MB
  unsigned short* Wkvt = (unsigned short*)(ws + 67108864 + 134217728);            // 16 MB
  unsigned short* Wot  = (unsigned short*)(ws + 67108864 + 134217728 + 16777216); // 8 MB

  cvt_f32_bf16<<<2048, 256, 0, stream>>>(e_seq, Ebf, (long)L_SEQ * D_IO);
  dim3 tb(32, 8);
  transpose_cvt<<<dim3(64, 64), tb, 0, stream>>>(Wk, Wkvt);
  transpose_cvt<<<dim3(64, 64), tb, 0, stream>>>(Wv, Wkvt + (size_t)D_IO * D_IO);
  transpose_cvt<<<dim3(64, 64), tb, 0, stream>>>(Wo, Wot);

  // KV = E * [Wk|Wv]   (M=16384, N=4096, K=2048), bf16 out
  gemm256<0><<<dim3(16, 64), 512, 0, stream>>>(Ebf, Wkvt, KV, nullptr, 4096, 4);

  // pooled (into Ebf, no longer needed)
  winpool<<<dim3(L_SEQ / 4, HEADS), 256, 0, stream>>>(KV, q, Ebf);

  // out = pooled * Wo + bo   (M=16384, N=2048, K=2048), f32 out + bias
  gemm256<1><<<dim3(8, 64), 512, 0, stream>>>(Ebf, Wot, out, bo, 2048, 3);
}

// Round 4
// 578.942 us; speedup vs baseline: 1.0440x; 1.0440x over previous
//
#include <hip/hip_runtime.h>
#include <hip/hip_bf16.h>

// Problem constants
#define L_SEQ   16384
#define D_IO    2048
#define HEADS   16
#define DHEAD   128
#define KDIM    2048
#define KT      (KDIM / 32)   // 64 K-tiles of BK=32

typedef __attribute__((ext_vector_type(8))) short short8;
typedef __attribute__((ext_vector_type(4))) float floatx4;

typedef const __attribute__((address_space(1))) unsigned int gu_t;
typedef __attribute__((address_space(3))) unsigned int lu_t;

__device__ __forceinline__ unsigned short f2bf(float f) {
  unsigned u = __float_as_uint(f);
  u += 0x7fffu + ((u >> 16) & 1u);   // RNE
  return (unsigned short)(u >> 16);
}
__device__ __forceinline__ float bf2f(unsigned short s) {
  return __uint_as_float(((unsigned)s) << 16);
}

// ---------------- f32 -> bf16 convert (vectorized, grid-stride) ----------------
__global__ __launch_bounds__(256)
void cvt_f32_bf16(const float* __restrict__ x, unsigned short* __restrict__ y, long n)
{
  for (long i = ((long)blockIdx.x * 256 + threadIdx.x) * 8; i < n;
       i += (long)gridDim.x * 256 * 8) {
    const float4 v0 = *(const float4*)(x + i);
    const float4 v1 = *(const float4*)(x + i + 4);
    uint4 r;
    r.x = (unsigned)f2bf(v0.x) | ((unsigned)f2bf(v0.y) << 16);
    r.y = (unsigned)f2bf(v0.z) | ((unsigned)f2bf(v0.w) << 16);
    r.z = (unsigned)f2bf(v1.x) | ((unsigned)f2bf(v1.y) << 16);
    r.w = (unsigned)f2bf(v1.z) | ((unsigned)f2bf(v1.w) << 16);
    *(uint4*)(y + i) = r;
  }
}

// ------------- transpose + convert: S[2048][2048] f32 -> D[2048][2048] bf16 (D = S^T) -------------
__global__ __launch_bounds__(256)
void transpose_cvt(const float* __restrict__ S, unsigned short* __restrict__ D)
{
  __shared__ float tile[32][33];
  const int bn = blockIdx.x * 32;
  const int bk = blockIdx.y * 32;
  const int tx = threadIdx.x, ty = threadIdx.y;  // (32, 8)
  #pragma unroll
  for (int i = 0; i < 32; i += 8)
    tile[ty + i][tx] = S[(size_t)(bk + ty + i) * D_IO + bn + tx];
  __syncthreads();
  #pragma unroll
  for (int i = 0; i < 32; i += 8)
    D[(size_t)(bn + ty + i) * D_IO + bk + tx] = f2bf(tile[tx][ty + i]);
}

// =====================================================================
// 256x256-tile bf16 GEMM, BK=32, 8 waves (2Mx4N), 4-deep LDS pipeline,
// counted vmcnt(8) (never drained in-loop), SINGLE phase per K-tile:
// 12 ds_reads issued at iter top (buffer guaranteed landed one barrier
// earlier), stage, vmcnt+barrier, then 32 MFMA with compiler-managed
// fine-grained lgkmcnt -> tail reads drain UNDER the leading MFMAs.
// T2 slot-XOR swizzle (round-2 math, measured 0 conflicts), T5 setprio,
// T1 XCD block swizzle.
// A: [M][2048] bf16 row-major. B: [N][2048] bf16 row-major (= B^T).
// C = A * B^T. EPI=0: bf16 out, EPI=1: f32 out + bias.
// =====================================================================
template<int EPI>
__global__ __launch_bounds__(512, 2)
void gemm256(const unsigned short* __restrict__ A,
             const unsigned short* __restrict__ B,
             void* __restrict__ Cout,
             const float* __restrict__ bias,
             const int ldc, const int bnShift)
{
  // 4 buffers x (A [256][32] 16KB | B [256][32] 16KB) = 128 KB
  __shared__ unsigned short lds[65536];

  const int t = threadIdx.x, lane = t & 63, wave = t >> 6;
  const int wm = wave >> 2, wn = wave & 3;       // 2 x 4 wave grid; per-wave out 128x64

  // T1: XCD-aware block swizzle (nwg % 8 == 0 for both GEMMs)
  const int nwg  = (int)(gridDim.x * gridDim.y);
  const int flat = (int)(blockIdx.y * gridDim.x + blockIdx.x);
  const int cpx  = nwg >> 3;
  const int swz  = (flat & 7) * cpx + (flat >> 3);
  const int bn = swz & ((1 << bnShift) - 1);
  const int bm = swz >> bnShift;

  const int fr = lane & 15, kq = lane >> 4;
  // T2 read-side swizzle: slot' = kq ^ ((row>>1)&3); row%16==fr for all frags
  const int rslot = ((kq ^ ((fr >> 1) & 3)) * 8);          // shorts

  // staging: per call 512thr x 16B = 128 rows; row = t>>2
  // inverse swizzle on SOURCE: src k-slot = (t&3) ^ ((row>>1)&3) = (t&3)^((t>>3)&3)
  const int srow  = t >> 2;
  const int sslot = (((t & 3) ^ ((t >> 3) & 3)) * 8);      // elems
  const unsigned short* aSrc = A + (size_t)(bm * 256 + srow) * KDIM + sslot;
  const unsigned short* bSrc = B + (size_t)(bn * 256 + srow) * KDIM + sslot;

  floatx4 acc[8][4];
  #pragma unroll
  for (int m = 0; m < 8; ++m)
    #pragma unroll
    for (int n = 0; n < 4; ++n) acc[m][n] = (floatx4)0.f;

  // dest: wave-uniform base + lane*16 (linear); src: per-lane (pre-swizzled)
#define STAGE_A(tile, ts) do { const int _b = (tile) & 3;                                   \
    __builtin_amdgcn_global_load_lds((gu_t*)(aSrc + (size_t)(ts) * 32),                     \
                                     (lu_t*)(lds + _b * 16384 + wave * 512), 16, 0, 0);     \
    __builtin_amdgcn_global_load_lds((gu_t*)(aSrc + (size_t)128 * KDIM + (size_t)(ts) * 32),\
                                     (lu_t*)(lds + _b * 16384 + 4096 + wave * 512), 16, 0, 0); } while (0)
#define STAGE_B(tile, ts) do { const int _b = (tile) & 3;                                   \
    __builtin_amdgcn_global_load_lds((gu_t*)(bSrc + (size_t)(ts) * 32),                     \
                                     (lu_t*)(lds + _b * 16384 + 8192 + wave * 512), 16, 0, 0); \
    __builtin_amdgcn_global_load_lds((gu_t*)(bSrc + (size_t)128 * KDIM + (size_t)(ts) * 32),\
                                     (lu_t*)(lds + _b * 16384 + 12288 + wave * 512), 16, 0, 0); } while (0)

  // prologue: stage tiles 0,1,2
  STAGE_A(0, 0); STAGE_B(0, 0);
  STAGE_A(1, 1); STAGE_B(1, 1);
  STAGE_A(2, 2); STAGE_B(2, 2);
  asm volatile("s_waitcnt vmcnt(8)" ::: "memory");   // tile 0 landed; tiles 1,2 in flight
  __builtin_amdgcn_s_barrier();

  for (int tt = 0; tt < KT; ++tt) {
    const int b = tt & 3;
    const int ts = (tt + 3 < KT) ? (tt + 3) : (KT - 1);  // tail: harmless dup re-stage
    const unsigned short* As = lds + b * 16384;
    const unsigned short* Bs = As + 8192;

    // 12 ds_read_b128: buffer tt landed (prev iter's vmcnt(8)+barrier).
    // No manual lgkmcnt: compiler emits fine-grained waits so the tail
    // reads drain under the leading MFMAs.
    short8 av[8], bv[4];
    #pragma unroll
    for (int m = 0; m < 8; ++m)
      av[m] = *(const short8*)(As + (wm * 128 + m * 16 + fr) * 32 + rslot);
    #pragma unroll
    for (int n = 0; n < 4; ++n)
      bv[n] = *(const short8*)(Bs + (wn * 64 + n * 16 + fr) * 32 + rslot);

    STAGE_A(tt + 3, ts);
    STAGE_B(tt + 3, ts);
    // tile tt+1 guaranteed landed; tiles tt+2, tt+3 (8 loads) stay in flight
    asm volatile("s_waitcnt vmcnt(8)" ::: "memory");
    __builtin_amdgcn_s_barrier();

    __builtin_amdgcn_s_setprio(1);
    #pragma unroll
    for (int m = 0; m < 8; ++m)
      #pragma unroll
      for (int n = 0; n < 4; ++n)
        acc[m][n] = __builtin_amdgcn_mfma_f32_16x16x32_bf16(av[m], bv[n], acc[m][n], 0, 0, 0);
    __builtin_amdgcn_s_setprio(0);
    __builtin_amdgcn_s_barrier();
  }
#undef STAGE_A
#undef STAGE_B

  // epilogue: C/D layout col = lane&15, row = (lane>>4)*4 + reg  [m89-verified]
  const int crow0 = bm * 256 + wm * 128 + kq * 4;
  const int ccol0 = bn * 256 + wn * 64 + fr;
  if (EPI == 0) {
    unsigned short* C = (unsigned short*)Cout;
    #pragma unroll
    for (int m = 0; m < 8; ++m)
      #pragma unroll
      for (int n = 0; n < 4; ++n)
        #pragma unroll
        for (int r = 0; r < 4; ++r)
          C[(size_t)(crow0 + m * 16 + r) * ldc + ccol0 + n * 16] = f2bf(acc[m][n][r]);
  } else {
    float* C = (float*)Cout;
    #pragma unroll
    for (int n = 0; n < 4; ++n) {
      const float bv_ = bias[ccol0 + n * 16];
      #pragma unroll
      for (int m = 0; m < 8; ++m)
        #pragma unroll
        for (int r = 0; r < 4; ++r)
          C[(size_t)(crow0 + m * 16 + r) * ldc + ccol0 + n * 16] = acc[m][n][r] + bv_;
    }
  }
}

// ---------------- sliding-window attention pool ----------------
__global__ __launch_bounds__(256)
void winpool(const unsigned short* __restrict__ KV,
             const float* __restrict__ Q,
             unsigned short* __restrict__ P)
{
  const int lane = threadIdx.x & 63, wid = threadIdx.x >> 6;
  // XCD-chunked swizzle on t-blocks: window re-reads hit same-XCD L2
  const int bx = ((int)blockIdx.x & 7) * ((int)gridDim.x >> 3) + ((int)blockIdx.x >> 3);
  const int t = bx * 4 + wid;
  const int h = blockIdx.y;
  const float qx = Q[h * DHEAD + lane * 2];
  const float qy = Q[h * DHEAD + lane * 2 + 1];
  const float scale = 0.08838834764831845f;  // 1/sqrt(128)

  float s[4];
  #pragma unroll
  for (int w = 0; w < 4; ++w) {
    const int idx = t - 3 + w;
    float part = 0.f;
    if (idx >= 0) {
      const unsigned kk = *(const unsigned*)(KV + (size_t)idx * 4096 + h * DHEAD + lane * 2);
      part = qx * bf2f((unsigned short)(kk & 0xffffu)) +
             qy * bf2f((unsigned short)(kk >> 16));
    }
    #pragma unroll
    for (int off = 32; off > 0; off >>= 1) part += __shfl_xor(part, off);
    s[w] = part * scale;
  }
  float mx = -3.0e38f;
  #pragma unroll
  for (int w = 0; w < 4; ++w) if (t - 3 + w >= 0) mx = fmaxf(mx, s[w]);
  float p[4], sum = 0.f;
  #pragma unroll
  for (int w = 0; w < 4; ++w) {
    p[w] = (t - 3 + w >= 0) ? expf(s[w] - mx) : 0.f;
    sum += p[w];
  }
  const float inv = 1.f / sum;

  float o0 = 0.f, o1 = 0.f;
  #pragma unroll
  for (int w = 0; w < 4; ++w) {
    const int idx = t - 3 + w;
    if (idx >= 0) {
      const unsigned vv = *(const unsigned*)(KV + (size_t)idx * 4096 + 2048 + h * DHEAD + lane * 2);
      o0 += p[w] * bf2f((unsigned short)(vv & 0xffffu));
      o1 += p[w] * bf2f((unsigned short)(vv >> 16));
    }
  }
  o0 *= inv; o1 *= inv;
  const unsigned outw = ((unsigned)f2bf(o1) << 16) | (unsigned)f2bf(o0);
  *(unsigned*)(P + (size_t)t * D_IO + h * DHEAD + lane * 2) = outw;
}

// ---------------- launch ----------------
extern "C" void kernel_launch(void* const* d_in, const int* in_sizes, int n_in,
                              void* d_out, int out_size, void* d_ws, size_t ws_size,
                              hipStream_t stream)
{
  const float* e_seq = (const float*)d_in[0];
  const float* q     = (const float*)d_in[1];
  const float* Wk    = (const float*)d_in[2];
  const float* Wv    = (const float*)d_in[3];
  const float* Wo    = (const float*)d_in[4];
  const float* bo    = (const float*)d_in[5];
  float* out = (float*)d_out;

  char* ws = (char*)d_ws;
  unsigned short* Ebf  = (unsigned short*)ws;                                     // 64 MB (E bf16; reused as pooled)
  unsigned short* KV   = (unsigned short*)(ws + 67108864);                        // 128 MB
  unsigned short* Wkvt = (unsigned short*)(ws + 67108864 + 134217728);            // 16 MB
  unsigned short* Wot  = (unsigned short*)(ws + 67108864 + 134217728 + 16777216); // 8 MB

  cvt_f32_bf16<<<2048, 256, 0, stream>>>(e_seq, Ebf, (long)L_SEQ * D_IO);
  dim3 tb(32, 8);
  transpose_cvt<<<dim3(64, 64), tb, 0, stream>>>(Wk, Wkvt);
  transpose_cvt<<<dim3(64, 64), tb, 0, stream>>>(Wv, Wkvt + (size_t)D_IO * D_IO);
  transpose_cvt<<<dim3(64, 64), tb, 0, stream>>>(Wo, Wot);

  // KV = E * [Wk|Wv]   (M=16384, N=4096, K=2048), bf16 out
  gemm256<0><<<dim3(16, 64), 512, 0, stream>>>(Ebf, Wkvt, KV, nullptr, 4096, 4);

  // pooled (into Ebf, no longer needed)
  winpool<<<dim3(L_SEQ / 4, HEADS), 256, 0, stream>>>(KV, q, Ebf);

  // out = pooled * Wo + bo   (M=16384, N=2048, K=2048), f32 out + bias
  gemm256<1><<<dim3(8, 64), 512, 0, stream>>>(Ebf, Wot, out, bo, 2048, 3);
}

// Round 5
// 561.689 us; speedup vs baseline: 1.0761x; 1.0307x over previous
//
#include <hip/hip_runtime.h>
#include <hip/hip_bf16.h>

// Problem constants
#define L_SEQ   16384
#define D_IO    2048
#define HEADS   16
#define DHEAD   128
#define KDIM    2048
#define KT64    (KDIM / 64)   // 32 K-tiles of BK=64

typedef __attribute__((ext_vector_type(8))) short short8;
typedef __attribute__((ext_vector_type(4))) float floatx4;

typedef const __attribute__((address_space(1))) unsigned int gu_t;
typedef __attribute__((address_space(3))) unsigned int lu_t;

__device__ __forceinline__ unsigned short f2bf(float f) {
  unsigned u = __float_as_uint(f);
  u += 0x7fffu + ((u >> 16) & 1u);   // RNE
  return (unsigned short)(u >> 16);
}
__device__ __forceinline__ float bf2f(unsigned short s) {
  return __uint_as_float(((unsigned)s) << 16);
}

// ---------------- f32 -> bf16 convert (vectorized, grid-stride) ----------------
__global__ __launch_bounds__(256)
void cvt_f32_bf16(const float* __restrict__ x, unsigned short* __restrict__ y, long n)
{
  for (long i = ((long)blockIdx.x * 256 + threadIdx.x) * 8; i < n;
       i += (long)gridDim.x * 256 * 8) {
    const float4 v0 = *(const float4*)(x + i);
    const float4 v1 = *(const float4*)(x + i + 4);
    uint4 r;
    r.x = (unsigned)f2bf(v0.x) | ((unsigned)f2bf(v0.y) << 16);
    r.y = (unsigned)f2bf(v0.z) | ((unsigned)f2bf(v0.w) << 16);
    r.z = (unsigned)f2bf(v1.x) | ((unsigned)f2bf(v1.y) << 16);
    r.w = (unsigned)f2bf(v1.z) | ((unsigned)f2bf(v1.w) << 16);
    *(uint4*)(y + i) = r;
  }
}

// ------------- transpose + convert: S[2048][2048] f32 -> D[2048][2048] bf16 (D = S^T) -------------
__global__ __launch_bounds__(256)
void transpose_cvt(const float* __restrict__ S, unsigned short* __restrict__ D)
{
  __shared__ float tile[32][33];
  const int bn = blockIdx.x * 32;
  const int bk = blockIdx.y * 32;
  const int tx = threadIdx.x, ty = threadIdx.y;  // (32, 8)
  #pragma unroll
  for (int i = 0; i < 32; i += 8)
    tile[ty + i][tx] = S[(size_t)(bk + ty + i) * D_IO + bn + tx];
  __syncthreads();
  #pragma unroll
  for (int i = 0; i < 32; i += 8)
    D[(size_t)(bn + ty + i) * D_IO + bk + tx] = f2bf(tile[tx][ty + i]);
}

// =====================================================================
// 256x256-tile bf16 GEMM, BK=64, 8 waves (2Mx4N), 2-slot LDS dbuf,
// 4 fine phases per K-tile (m201-style): each phase = {4-12 ds_reads ->
// barrier -> lgkmcnt(0) -> 16 MFMA -> barrier}; 8 stage calls for tile
// t+1 front-loaded in ph0/ph1; full vmcnt drain deferred to after ph3's
// MFMA (~3 phases of slack). slot^=(row&7) XOR swizzle (inverse-swizzled
// global source, swizzled ds_read). T5 setprio, T1 XCD swizzle.
// A: [M][2048] bf16 row-major. B: [N][2048] bf16 row-major (= B^T).
// C = A * B^T. EPI=0: bf16 out, EPI=1: f32 out + bias.
// =====================================================================
template<int EPI>
__global__ __launch_bounds__(512, 2)
void gemm256(const unsigned short* __restrict__ A,
             const unsigned short* __restrict__ B,
             void* __restrict__ Cout,
             const float* __restrict__ bias,
             const int ldc, const int bnShift)
{
  // 2 slots x (A [256][64] 32KB + B [256][64] 32KB) = 128 KB
  __shared__ unsigned short lds[65536];

  const int t = threadIdx.x, lane = t & 63, wave = t >> 6;
  const int wm = wave >> 2, wn = wave & 3;       // 2 x 4 wave grid; per-wave out 128x64

  // T1: XCD-aware block swizzle (nwg % 8 == 0 for both GEMMs)
  const int nwg  = (int)(gridDim.x * gridDim.y);
  const int flat = (int)(blockIdx.y * gridDim.x + blockIdx.x);
  const int cpx  = nwg >> 3;
  const int swz  = (flat & 7) * cpx + (flat >> 3);
  const int bn = swz & ((1 << bnShift) - 1);
  const int bm = swz >> bnShift;

  const int fr = lane & 15, kq = lane >> 4;
  // swizzled 16B-slot offset (shorts) for kk=0; kk=1 is ^32 (slot bit2)
  const int sl0 = ((kq ^ (fr & 7)) & 7) * 8;

  // staging: 512 thr x 16B = 8KB per call = 64 rows x 128B; row = t>>3, slot = t&7
  // inverse swizzle on SOURCE: src k-slot = (t&7) ^ (row&7)
  const int srow  = t >> 3;                          // 0..63 within call-chunk
  const int sslot = (((t & 7) ^ (srow & 7)) & 7) * 8; // elems
  const unsigned short* aSrc = A + (size_t)(bm * 256 + srow) * KDIM + sslot;
  const unsigned short* bSrc = B + (size_t)(bn * 256 + srow) * KDIM + sslot;

  floatx4 acc[8][4];
  #pragma unroll
  for (int m = 0; m < 8; ++m)
    #pragma unroll
    for (int n = 0; n < 4; ++n) acc[m][n] = (floatx4)0.f;

  // 4 calls cover one 256x64 tile (A or B); dest linear, src pre-swizzled
#define STAGE4(srcbase, dstoff, ts) do {                                                     \
    __builtin_amdgcn_global_load_lds((gu_t*)((srcbase) + (size_t)(ts) * 64),                 \
                                     (lu_t*)(lds + (dstoff) + wave * 512), 16, 0, 0);        \
    __builtin_amdgcn_global_load_lds((gu_t*)((srcbase) + (size_t)(ts) * 64 + (size_t)64 * KDIM),  \
                                     (lu_t*)(lds + (dstoff) + 4096 + wave * 512), 16, 0, 0); \
    __builtin_amdgcn_global_load_lds((gu_t*)((srcbase) + (size_t)(ts) * 64 + (size_t)128 * KDIM), \
                                     (lu_t*)(lds + (dstoff) + 8192 + wave * 512), 16, 0, 0); \
    __builtin_amdgcn_global_load_lds((gu_t*)((srcbase) + (size_t)(ts) * 64 + (size_t)192 * KDIM), \
                                     (lu_t*)(lds + (dstoff) + 12288 + wave * 512), 16, 0, 0); } while (0)

  // prologue: stage tile 0 into slot 0
  STAGE4(aSrc, 0, 0);
  STAGE4(bSrc, 16384, 0);
  asm volatile("s_waitcnt vmcnt(0)" ::: "memory");
  __builtin_amdgcn_s_barrier();

  short8 aq[4][2], bq0[2][2], bq1[2][2];

  for (int tt = 0; tt < KT64; ++tt) {
    const int s = tt & 1;
    const int ts = (tt + 1 < KT64) ? (tt + 1) : tt;   // tail: harmless dup re-stage
    const unsigned short* As = lds + s * 32768;
    const unsigned short* Bs = As + 16384;
    const unsigned short* Ar = As + (wm * 128 + fr) * 64;
    const unsigned short* Br = Bs + (wn * 64 + fr) * 64;
    const int d = (s ^ 1) * 32768;

    // ---- ph0: read A m0-3 (8) + B n0-1 (4); stage A(t+1); MFMA m0-3 x n0-1 ----
    #pragma unroll
    for (int m = 0; m < 4; ++m) {
      aq[m][0] = *(const short8*)(Ar + m * 1024 + sl0);
      aq[m][1] = *(const short8*)(Ar + m * 1024 + (sl0 ^ 32));
    }
    #pragma unroll
    for (int n = 0; n < 2; ++n) {
      bq0[n][0] = *(const short8*)(Br + n * 1024 + sl0);
      bq0[n][1] = *(const short8*)(Br + n * 1024 + (sl0 ^ 32));
    }
    STAGE4(aSrc, d, ts);
    __builtin_amdgcn_s_barrier();
    asm volatile("s_waitcnt lgkmcnt(0)" ::: "memory");
    __builtin_amdgcn_sched_barrier(0);
    __builtin_amdgcn_s_setprio(1);
    #pragma unroll
    for (int m = 0; m < 4; ++m)
      #pragma unroll
      for (int n = 0; n < 2; ++n) {
        acc[m][n] = __builtin_amdgcn_mfma_f32_16x16x32_bf16(aq[m][0], bq0[n][0], acc[m][n], 0, 0, 0);
        acc[m][n] = __builtin_amdgcn_mfma_f32_16x16x32_bf16(aq[m][1], bq0[n][1], acc[m][n], 0, 0, 0);
      }
    __builtin_amdgcn_s_setprio(0);
    __builtin_amdgcn_s_barrier();

    // ---- ph1: read B n2-3 (4); stage B(t+1); MFMA m0-3 x n2-3 ----
    #pragma unroll
    for (int n = 0; n < 2; ++n) {
      bq1[n][0] = *(const short8*)(Br + (2 + n) * 1024 + sl0);
      bq1[n][1] = *(const short8*)(Br + (2 + n) * 1024 + (sl0 ^ 32));
    }
    STAGE4(bSrc, d + 16384, ts);
    __builtin_amdgcn_s_barrier();
    asm volatile("s_waitcnt lgkmcnt(0)" ::: "memory");
    __builtin_amdgcn_sched_barrier(0);
    __builtin_amdgcn_s_setprio(1);
    #pragma unroll
    for (int m = 0; m < 4; ++m)
      #pragma unroll
      for (int n = 0; n < 2; ++n) {
        acc[m][2 + n] = __builtin_amdgcn_mfma_f32_16x16x32_bf16(aq[m][0], bq1[n][0], acc[m][2 + n], 0, 0, 0);
        acc[m][2 + n] = __builtin_amdgcn_mfma_f32_16x16x32_bf16(aq[m][1], bq1[n][1], acc[m][2 + n], 0, 0, 0);
      }
    __builtin_amdgcn_s_setprio(0);
    __builtin_amdgcn_s_barrier();

    // ---- ph2: read A m4-7 (8); MFMA m4-7 x n2-3 ----
    #pragma unroll
    for (int m = 0; m < 4; ++m) {
      aq[m][0] = *(const short8*)(Ar + (4 + m) * 1024 + sl0);
      aq[m][1] = *(const short8*)(Ar + (4 + m) * 1024 + (sl0 ^ 32));
    }
    __builtin_amdgcn_s_barrier();
    asm volatile("s_waitcnt lgkmcnt(0)" ::: "memory");
    __builtin_amdgcn_sched_barrier(0);
    __builtin_amdgcn_s_setprio(1);
    #pragma unroll
    for (int m = 0; m < 4; ++m)
      #pragma unroll
      for (int n = 0; n < 2; ++n) {
        acc[4 + m][2 + n] = __builtin_amdgcn_mfma_f32_16x16x32_bf16(aq[m][0], bq1[n][0], acc[4 + m][2 + n], 0, 0, 0);
        acc[4 + m][2 + n] = __builtin_amdgcn_mfma_f32_16x16x32_bf16(aq[m][1], bq1[n][1], acc[4 + m][2 + n], 0, 0, 0);
      }
    __builtin_amdgcn_s_setprio(0);
    __builtin_amdgcn_s_barrier();

    // ---- ph3: re-read B n0-1 (4); MFMA m4-7 x n0-1; drain stages; bar ----
    #pragma unroll
    for (int n = 0; n < 2; ++n) {
      bq0[n][0] = *(const short8*)(Br + n * 1024 + sl0);
      bq0[n][1] = *(const short8*)(Br + n * 1024 + (sl0 ^ 32));
    }
    __builtin_amdgcn_s_barrier();
    asm volatile("s_waitcnt lgkmcnt(0)" ::: "memory");
    __builtin_amdgcn_sched_barrier(0);
    __builtin_amdgcn_s_setprio(1);
    #pragma unroll
    for (int m = 0; m < 4; ++m)
      #pragma unroll
      for (int n = 0; n < 2; ++n) {
        acc[4 + m][n] = __builtin_amdgcn_mfma_f32_16x16x32_bf16(aq[m][0], bq0[n][0], acc[4 + m][n], 0, 0, 0);
        acc[4 + m][n] = __builtin_amdgcn_mfma_f32_16x16x32_bf16(aq[m][1], bq0[n][1], acc[4 + m][n], 0, 0, 0);
      }
    __builtin_amdgcn_s_setprio(0);
    // stages were issued >= 2 phases ago -> this drain is nearly free
    asm volatile("s_waitcnt vmcnt(0)" ::: "memory");
    __builtin_amdgcn_s_barrier();
  }
#undef STAGE4

  // epilogue: C/D layout col = lane&15, row = (lane>>4)*4 + reg  [m89-verified]
  const int crow0 = bm * 256 + wm * 128 + kq * 4;
  const int ccol0 = bn * 256 + wn * 64 + fr;
  if (EPI == 0) {
    unsigned short* C = (unsigned short*)Cout;
    #pragma unroll
    for (int m = 0; m < 8; ++m)
      #pragma unroll
      for (int n = 0; n < 4; ++n)
        #pragma unroll
        for (int r = 0; r < 4; ++r)
          C[(size_t)(crow0 + m * 16 + r) * ldc + ccol0 + n * 16] = f2bf(acc[m][n][r]);
  } else {
    float* C = (float*)Cout;
    #pragma unroll
    for (int n = 0; n < 4; ++n) {
      const float bv_ = bias[ccol0 + n * 16];
      #pragma unroll
      for (int m = 0; m < 8; ++m)
        #pragma unroll
        for (int r = 0; r < 4; ++r)
          C[(size_t)(crow0 + m * 16 + r) * ldc + ccol0 + n * 16] = acc[m][n][r] + bv_;
    }
  }
}

// ---------------- sliding-window attention pool ----------------
__global__ __launch_bounds__(256)
void winpool(const unsigned short* __restrict__ KV,
             const float* __restrict__ Q,
             unsigned short* __restrict__ P)
{
  const int lane = threadIdx.x & 63, wid = threadIdx.x >> 6;
  // XCD-chunked swizzle on t-blocks: window re-reads hit same-XCD L2
  const int bx = ((int)blockIdx.x & 7) * ((int)gridDim.x >> 3) + ((int)blockIdx.x >> 3);
  const int t = bx * 4 + wid;
  const int h = blockIdx.y;
  const float qx = Q[h * DHEAD + lane * 2];
  const float qy = Q[h * DHEAD + lane * 2 + 1];
  const float scale = 0.08838834764831845f;  // 1/sqrt(128)

  float s[4];
  #pragma unroll
  for (int w = 0; w < 4; ++w) {
    const int idx = t - 3 + w;
    float part = 0.f;
    if (idx >= 0) {
      const unsigned kk = *(const unsigned*)(KV + (size_t)idx * 4096 + h * DHEAD + lane * 2);
      part = qx * bf2f((unsigned short)(kk & 0xffffu)) +
             qy * bf2f((unsigned short)(kk >> 16));
    }
    #pragma unroll
    for (int off = 32; off > 0; off >>= 1) part += __shfl_xor(part, off);
    s[w] = part * scale;
  }
  float mx = -3.0e38f;
  #pragma unroll
  for (int w = 0; w < 4; ++w) if (t - 3 + w >= 0) mx = fmaxf(mx, s[w]);
  float p[4], sum = 0.f;
  #pragma unroll
  for (int w = 0; w < 4; ++w) {
    p[w] = (t - 3 + w >= 0) ? expf(s[w] - mx) : 0.f;
    sum += p[w];
  }
  const float inv = 1.f / sum;

  float o0 = 0.f, o1 = 0.f;
  #pragma unroll
  for (int w = 0; w < 4; ++w) {
    const int idx = t - 3 + w;
    if (idx >= 0) {
      const unsigned vv = *(const unsigned*)(KV + (size_t)idx * 4096 + 2048 + h * DHEAD + lane * 2);
      o0 += p[w] * bf2f((unsigned short)(vv & 0xffffu));
      o1 += p[w] * bf2f((unsigned short)(vv >> 16));
    }
  }
  o0 *= inv; o1 *= inv;
  const unsigned outw = ((unsigned)f2bf(o1) << 16) | (unsigned)f2bf(o0);
  *(unsigned*)(P + (size_t)t * D_IO + h * DHEAD + lane * 2) = outw;
}

// ---------------- launch ----------------
extern "C" void kernel_launch(void* const* d_in, const int* in_sizes, int n_in,
                              void* d_out, int out_size, void* d_ws, size_t ws_size,
                              hipStream_t stream)
{
  const float* e_seq = (const float*)d_in[0];
  const float* q     = (const float*)d_in[1];
  const float* Wk    = (const float*)d_in[2];
  const float* Wv    = (const float*)d_in[3];
  const float* Wo    = (const float*)d_in[4];
  const float* bo    = (const float*)d_in[5];
  float* out = (float*)d_out;

  char* ws = (char*)d_ws;
  unsigned short* Ebf  = (unsigned short*)ws;                                     // 64 MB (E bf16; reused as pooled)
  unsigned short* KV   = (unsigned short*)(ws + 67108864);                        // 128 MB
  unsigned short* Wkvt = (unsigned short*)(ws + 67108864 + 134217728);            // 16 MB
  unsigned short* Wot  = (unsigned short*)(ws + 67108864 + 134217728 + 16777216); // 8 MB

  cvt_f32_bf16<<<2048, 256, 0, stream>>>(e_seq, Ebf, (long)L_SEQ * D_IO);
  dim3 tb(32, 8);
  transpose_cvt<<<dim3(64, 64), tb, 0, stream>>>(Wk, Wkvt);
  transpose_cvt<<<dim3(64, 64), tb, 0, stream>>>(Wv, Wkvt + (size_t)D_IO * D_IO);
  transpose_cvt<<<dim3(64, 64), tb, 0, stream>>>(Wo, Wot);

  // KV = E * [Wk|Wv]   (M=16384, N=4096, K=2048), bf16 out
  gemm256<0><<<dim3(16, 64), 512, 0, stream>>>(Ebf, Wkvt, KV, nullptr, 4096, 4);

  // pooled (into Ebf, no longer needed)
  winpool<<<dim3(L_SEQ / 4, HEADS), 256, 0, stream>>>(KV, q, Ebf);

  // out = pooled * Wo + bo   (M=16384, N=2048, K=2048), f32 out + bias
  gemm256<1><<<dim3(8, 64), 512, 0, stream>>>(Ebf, Wot, out, bo, 2048, 3);
}

// Round 6
// 546.672 us; speedup vs baseline: 1.1057x; 1.0275x over previous
//
#include <hip/hip_runtime.h>
#include <hip/hip_bf16.h>

// Problem constants
#define L_SEQ   16384
#define D_IO    2048
#define HEADS   16
#define DHEAD   128
#define KDIM    2048
#define KT64    (KDIM / 64)   // 32 K-tiles of BK=64

typedef __attribute__((ext_vector_type(8))) short short8;
typedef __attribute__((ext_vector_type(4))) float floatx4;

typedef const __attribute__((address_space(1))) unsigned int gu_t;
typedef __attribute__((address_space(3))) unsigned int lu_t;

__device__ __forceinline__ unsigned short f2bf(float f) {
  unsigned u = __float_as_uint(f);
  u += 0x7fffu + ((u >> 16) & 1u);   // RNE
  return (unsigned short)(u >> 16);
}
__device__ __forceinline__ float bf2f(unsigned short s) {
  return __uint_as_float(((unsigned)s) << 16);
}

// ---------------- f32 -> bf16 convert (vectorized, grid-stride) ----------------
__global__ __launch_bounds__(256)
void cvt_f32_bf16(const float* __restrict__ x, unsigned short* __restrict__ y, long n)
{
  for (long i = ((long)blockIdx.x * 256 + threadIdx.x) * 8; i < n;
       i += (long)gridDim.x * 256 * 8) {
    const float4 v0 = *(const float4*)(x + i);
    const float4 v1 = *(const float4*)(x + i + 4);
    uint4 r;
    r.x = (unsigned)f2bf(v0.x) | ((unsigned)f2bf(v0.y) << 16);
    r.y = (unsigned)f2bf(v0.z) | ((unsigned)f2bf(v0.w) << 16);
    r.z = (unsigned)f2bf(v1.x) | ((unsigned)f2bf(v1.y) << 16);
    r.w = (unsigned)f2bf(v1.z) | ((unsigned)f2bf(v1.w) << 16);
    *(uint4*)(y + i) = r;
  }
}

// ------------- transpose + convert: S[2048][2048] f32 -> D[2048][2048] bf16 (D = S^T) -------------
__global__ __launch_bounds__(256)
void transpose_cvt(const float* __restrict__ S, unsigned short* __restrict__ D)
{
  __shared__ float tile[32][33];
  const int bn = blockIdx.x * 32;
  const int bk = blockIdx.y * 32;
  const int tx = threadIdx.x, ty = threadIdx.y;  // (32, 8)
  #pragma unroll
  for (int i = 0; i < 32; i += 8)
    tile[ty + i][tx] = S[(size_t)(bk + ty + i) * D_IO + bn + tx];
  __syncthreads();
  #pragma unroll
  for (int i = 0; i < 32; i += 8)
    D[(size_t)(bn + ty + i) * D_IO + bk + tx] = f2bf(tile[tx][ty + i]);
}

// =====================================================================
// 256x256-tile bf16 GEMM, BK=64, 8 waves (2Mx4N), 2-slot LDS dbuf,
// 4 fine phases per K-tile, COUNTED vmcnt (T4 — never drained in-loop).
// LDS slot = 8 quarter regions (Aq0-3, Bq0-3; 1 stage call each, 8KB).
// Stage order per tile matches next tile's read order:
//   ph0: Aq0,Aq2 (read next ph0)   ph1: Bq0,Bq1 (read next ph0/ph1)
//   ph2: Bq2,Bq3                    ph3: Aq1,Aq3 (read next ph2)
// Waits: end-ph1 vmcnt(4) -> current tile's Aq1/Aq3 landed (for ph2);
//        end-ph3 vmcnt(2) -> next tile's Aq0,Aq2,Bq0-3 landed (for ph0),
//        its Aq1/Aq3 stay in flight across the boundary.
// slot^=(row&7) XOR swizzle (inverse-swizzled global source, swizzled
// ds_read; measured 0 conflicts). T5 setprio, T1 XCD swizzle.
// A: [M][2048] bf16 row-major. B: [N][2048] bf16 row-major (= B^T).
// C = A * B^T. EPI=0: bf16 out, EPI=1: f32 out + bias.
// =====================================================================
template<int EPI>
__global__ __launch_bounds__(512, 2)
void gemm256(const unsigned short* __restrict__ A,
             const unsigned short* __restrict__ B,
             void* __restrict__ Cout,
             const float* __restrict__ bias,
             const int ldc, const int bnShift)
{
  // 2 slots x (A 4x8KB + B 4x8KB) = 128 KB
  __shared__ unsigned short lds[65536];

  const int t = threadIdx.x, lane = t & 63, wave = t >> 6;
  const int wm = wave >> 2, wn = wave & 3;       // 2 x 4 wave grid; per-wave out 128x64

  // T1: XCD-aware block swizzle (nwg % 8 == 0 for both GEMMs)
  const int nwg  = (int)(gridDim.x * gridDim.y);
  const int flat = (int)(blockIdx.y * gridDim.x + blockIdx.x);
  const int cpx  = nwg >> 3;
  const int swz  = (flat & 7) * cpx + (flat >> 3);
  const int bn = swz & ((1 << bnShift) - 1);
  const int bm = swz >> bnShift;

  const int fr = lane & 15, kq = lane >> 4;
  // swizzled 16B-slot offset (shorts) for kk=0; kk=1 is ^32 (slot bit2)
  const int sl0 = ((kq ^ (fr & 7)) & 7) * 8;

  // staging: 512 thr x 16B = 8KB per call = 64 rows x 128B; row = t>>3, slot = t&7
  // inverse swizzle on SOURCE: src k-slot = (t&7) ^ (row&7)
  const int srow  = t >> 3;                           // 0..63 within quarter
  const int sslot = (((t & 7) ^ (srow & 7)) & 7) * 8; // elems
  const unsigned short* aSrc = A + (size_t)(bm * 256 + srow) * KDIM + sslot;
  const unsigned short* bSrc = B + (size_t)(bn * 256 + srow) * KDIM + sslot;

  floatx4 acc[8][4];
  #pragma unroll
  for (int m = 0; m < 8; ++m)
    #pragma unroll
    for (int n = 0; n < 4; ++n) acc[m][n] = (floatx4)0.f;

  // stage one 64-row quarter (q = quarter index within the 256-row panel)
#define STAGE1(srcbase, q, dstoff, ts)                                                        \
    __builtin_amdgcn_global_load_lds((gu_t*)((srcbase) + (size_t)(ts) * 64 +                  \
                                             (size_t)(q) * 64 * KDIM),                        \
                                     (lu_t*)(lds + (dstoff) + wave * 512), 16, 0, 0)

  // prologue: stage tile 0 in canonical order [Aq0,Aq2,Bq0,Bq1,Bq2,Bq3,Aq1,Aq3]
  STAGE1(aSrc, 0, 0, 0);      STAGE1(aSrc, 2, 8192, 0);
  STAGE1(bSrc, 0, 16384, 0);  STAGE1(bSrc, 1, 20480, 0);
  STAGE1(bSrc, 2, 24576, 0);  STAGE1(bSrc, 3, 28672, 0);
  STAGE1(aSrc, 1, 4096, 0);   STAGE1(aSrc, 3, 12288, 0);
  asm volatile("s_waitcnt vmcnt(2)" ::: "memory");   // Aq0,Aq2,Bq0-3 landed; Aq1,Aq3 in flight
  __builtin_amdgcn_s_barrier();

  short8 aq[4][2], bq0[2][2], bq1[2][2];

  for (int tt = 0; tt < KT64; ++tt) {
    const int s = tt & 1;
    const int ts = (tt + 1 < KT64) ? (tt + 1) : tt;   // tail: harmless dup re-stage
    const int d = (s ^ 1) * 32768;
    const unsigned short* As = lds + s * 32768;
    const unsigned short* Bs = As + 16384;
    const unsigned short* ArLo = As + (wm * 2) * 4096 + fr * 64;   // Aq(wm*2):   m0-3
    const unsigned short* ArHi = ArLo + 4096;                      // Aq(wm*2+1): m4-7
    const unsigned short* Br   = Bs + wn * 4096 + fr * 64;         // Bq(wn)

    // ---- ph0: read A m0-3 (8) + B n0-1 (4); stage Aq0',Aq2'; MFMA m0-3 x n0-1 ----
    #pragma unroll
    for (int m = 0; m < 4; ++m) {
      aq[m][0] = *(const short8*)(ArLo + m * 1024 + sl0);
      aq[m][1] = *(const short8*)(ArLo + m * 1024 + (sl0 ^ 32));
    }
    #pragma unroll
    for (int n = 0; n < 2; ++n) {
      bq0[n][0] = *(const short8*)(Br + n * 1024 + sl0);
      bq0[n][1] = *(const short8*)(Br + n * 1024 + (sl0 ^ 32));
    }
    STAGE1(aSrc, 0, d, ts);
    STAGE1(aSrc, 2, d + 8192, ts);
    __builtin_amdgcn_s_barrier();
    asm volatile("s_waitcnt lgkmcnt(0)" ::: "memory");
    __builtin_amdgcn_sched_barrier(0);
    __builtin_amdgcn_s_setprio(1);
    #pragma unroll
    for (int m = 0; m < 4; ++m)
      #pragma unroll
      for (int n = 0; n < 2; ++n) {
        acc[m][n] = __builtin_amdgcn_mfma_f32_16x16x32_bf16(aq[m][0], bq0[n][0], acc[m][n], 0, 0, 0);
        acc[m][n] = __builtin_amdgcn_mfma_f32_16x16x32_bf16(aq[m][1], bq0[n][1], acc[m][n], 0, 0, 0);
      }
    __builtin_amdgcn_s_setprio(0);
    __builtin_amdgcn_s_barrier();

    // ---- ph1: read B n2-3 (4); stage Bq0',Bq1'; MFMA m0-3 x n2-3; vmcnt(4) ----
    #pragma unroll
    for (int n = 0; n < 2; ++n) {
      bq1[n][0] = *(const short8*)(Br + (2 + n) * 1024 + sl0);
      bq1[n][1] = *(const short8*)(Br + (2 + n) * 1024 + (sl0 ^ 32));
    }
    STAGE1(bSrc, 0, d + 16384, ts);
    STAGE1(bSrc, 1, d + 20480, ts);
    __builtin_amdgcn_s_barrier();
    asm volatile("s_waitcnt lgkmcnt(0)" ::: "memory");
    __builtin_amdgcn_sched_barrier(0);
    __builtin_amdgcn_s_setprio(1);
    #pragma unroll
    for (int m = 0; m < 4; ++m)
      #pragma unroll
      for (int n = 0; n < 2; ++n) {
        acc[m][2 + n] = __builtin_amdgcn_mfma_f32_16x16x32_bf16(aq[m][0], bq1[n][0], acc[m][2 + n], 0, 0, 0);
        acc[m][2 + n] = __builtin_amdgcn_mfma_f32_16x16x32_bf16(aq[m][1], bq1[n][1], acc[m][2 + n], 0, 0, 0);
      }
    __builtin_amdgcn_s_setprio(0);
    // current tile's Aq1,Aq3 (staged last tile's ph3) now needed next phase
    asm volatile("s_waitcnt vmcnt(4)" ::: "memory");
    __builtin_amdgcn_s_barrier();

    // ---- ph2: read A m4-7 (8); stage Bq2',Bq3'; MFMA m4-7 x n2-3 ----
    #pragma unroll
    for (int m = 0; m < 4; ++m) {
      aq[m][0] = *(const short8*)(ArHi + m * 1024 + sl0);
      aq[m][1] = *(const short8*)(ArHi + m * 1024 + (sl0 ^ 32));
    }
    STAGE1(bSrc, 2, d + 24576, ts);
    STAGE1(bSrc, 3, d + 28672, ts);
    __builtin_amdgcn_s_barrier();
    asm volatile("s_waitcnt lgkmcnt(0)" ::: "memory");
    __builtin_amdgcn_sched_barrier(0);
    __builtin_amdgcn_s_setprio(1);
    #pragma unroll
    for (int m = 0; m < 4; ++m)
      #pragma unroll
      for (int n = 0; n < 2; ++n) {
        acc[4 + m][2 + n] = __builtin_amdgcn_mfma_f32_16x16x32_bf16(aq[m][0], bq1[n][0], acc[4 + m][2 + n], 0, 0, 0);
        acc[4 + m][2 + n] = __builtin_amdgcn_mfma_f32_16x16x32_bf16(aq[m][1], bq1[n][1], acc[4 + m][2 + n], 0, 0, 0);
      }
    __builtin_amdgcn_s_setprio(0);
    __builtin_amdgcn_s_barrier();

    // ---- ph3: no reads (bq0 kept live); stage Aq1',Aq3'; MFMA m4-7 x n0-1; vmcnt(2) ----
    STAGE1(aSrc, 1, d + 4096, ts);
    STAGE1(aSrc, 3, d + 12288, ts);
    __builtin_amdgcn_s_setprio(1);
    #pragma unroll
    for (int m = 0; m < 4; ++m)
      #pragma unroll
      for (int n = 0; n < 2; ++n) {
        acc[4 + m][n] = __builtin_amdgcn_mfma_f32_16x16x32_bf16(aq[m][0], bq0[n][0], acc[4 + m][n], 0, 0, 0);
        acc[4 + m][n] = __builtin_amdgcn_mfma_f32_16x16x32_bf16(aq[m][1], bq0[n][1], acc[4 + m][n], 0, 0, 0);
      }
    __builtin_amdgcn_s_setprio(0);
    // next tile's Aq0,Aq2,Bq0-3 landed; its Aq1,Aq3 stay in flight
    asm volatile("s_waitcnt vmcnt(2)" ::: "memory");
    __builtin_amdgcn_s_barrier();
  }
#undef STAGE1

  // drain remaining in-flight LDS writes before exit (dup re-stages of last tile)
  asm volatile("s_waitcnt vmcnt(0)" ::: "memory");

  // epilogue: C/D layout col = lane&15, row = (lane>>4)*4 + reg  [m89-verified]
  const int crow0 = bm * 256 + wm * 128 + kq * 4;
  const int ccol0 = bn * 256 + wn * 64 + fr;
  if (EPI == 0) {
    unsigned short* C = (unsigned short*)Cout;
    #pragma unroll
    for (int m = 0; m < 8; ++m)
      #pragma unroll
      for (int n = 0; n < 4; ++n)
        #pragma unroll
        for (int r = 0; r < 4; ++r)
          C[(size_t)(crow0 + m * 16 + r) * ldc + ccol0 + n * 16] = f2bf(acc[m][n][r]);
  } else {
    float* C = (float*)Cout;
    #pragma unroll
    for (int n = 0; n < 4; ++n) {
      const float bv_ = bias[ccol0 + n * 16];
      #pragma unroll
      for (int m = 0; m < 8; ++m)
        #pragma unroll
        for (int r = 0; r < 4; ++r)
          C[(size_t)(crow0 + m * 16 + r) * ldc + ccol0 + n * 16] = acc[m][n][r] + bv_;
    }
  }
}

// ---------------- sliding-window attention pool ----------------
__global__ __launch_bounds__(256)
void winpool(const unsigned short* __restrict__ KV,
             const float* __restrict__ Q,
             unsigned short* __restrict__ P)
{
  const int lane = threadIdx.x & 63, wid = threadIdx.x >> 6;
  // XCD-chunked swizzle on t-blocks: window re-reads hit same-XCD L2
  const int bx = ((int)blockIdx.x & 7) * ((int)gridDim.x >> 3) + ((int)blockIdx.x >> 3);
  const int t = bx * 4 + wid;
  const int h = blockIdx.y;
  const float qx = Q[h * DHEAD + lane * 2];
  const float qy = Q[h * DHEAD + lane * 2 + 1];
  const float scale = 0.08838834764831845f;  // 1/sqrt(128)

  float s[4];
  #pragma unroll
  for (int w = 0; w < 4; ++w) {
    const int idx = t - 3 + w;
    float part = 0.f;
    if (idx >= 0) {
      const unsigned kk = *(const unsigned*)(KV + (size_t)idx * 4096 + h * DHEAD + lane * 2);
      part = qx * bf2f((unsigned short)(kk & 0xffffu)) +
             qy * bf2f((unsigned short)(kk >> 16));
    }
    #pragma unroll
    for (int off = 32; off > 0; off >>= 1) part += __shfl_xor(part, off);
    s[w] = part * scale;
  }
  float mx = -3.0e38f;
  #pragma unroll
  for (int w = 0; w < 4; ++w) if (t - 3 + w >= 0) mx = fmaxf(mx, s[w]);
  float p[4], sum = 0.f;
  #pragma unroll
  for (int w = 0; w < 4; ++w) {
    p[w] = (t - 3 + w >= 0) ? expf(s[w] - mx) : 0.f;
    sum += p[w];
  }
  const float inv = 1.f / sum;

  float o0 = 0.f, o1 = 0.f;
  #pragma unroll
  for (int w = 0; w < 4; ++w) {
    const int idx = t - 3 + w;
    if (idx >= 0) {
      const unsigned vv = *(const unsigned*)(KV + (size_t)idx * 4096 + 2048 + h * DHEAD + lane * 2);
      o0 += p[w] * bf2f((unsigned short)(vv & 0xffffu));
      o1 += p[w] * bf2f((unsigned short)(vv >> 16));
    }
  }
  o0 *= inv; o1 *= inv;
  const unsigned outw = ((unsigned)f2bf(o1) << 16) | (unsigned)f2bf(o0);
  *(unsigned*)(P + (size_t)t * D_IO + h * DHEAD + lane * 2) = outw;
}

// ---------------- launch ----------------
extern "C" void kernel_launch(void* const* d_in, const int* in_sizes, int n_in,
                              void* d_out, int out_size, void* d_ws, size_t ws_size,
                              hipStream_t stream)
{
  const float* e_seq = (const float*)d_in[0];
  const float* q     = (const float*)d_in[1];
  const float* Wk    = (const float*)d_in[2];
  const float* Wv    = (const float*)d_in[3];
  const float* Wo    = (const float*)d_in[4];
  const float* bo    = (const float*)d_in[5];
  float* out = (float*)d_out;

  char* ws = (char*)d_ws;
  unsigned short* Ebf  = (unsigned short*)ws;                                     // 64 MB (E bf16; reused as pooled)
  unsigned short* KV   = (unsigned short*)(ws + 67108864);                        // 128 MB
  unsigned short* Wkvt = (unsigned short*)(ws + 67108864 + 134217728);            // 16 MB
  unsigned short* Wot  = (unsigned short*)(ws + 67108864 + 134217728 + 16777216); // 8 MB

  cvt_f32_bf16<<<2048, 256, 0, stream>>>(e_seq, Ebf, (long)L_SEQ * D_IO);
  dim3 tb(32, 8);
  transpose_cvt<<<dim3(64, 64), tb, 0, stream>>>(Wk, Wkvt);
  transpose_cvt<<<dim3(64, 64), tb, 0, stream>>>(Wv, Wkvt + (size_t)D_IO * D_IO);
  transpose_cvt<<<dim3(64, 64), tb, 0, stream>>>(Wo, Wot);

  // KV = E * [Wk|Wv]   (M=16384, N=4096, K=2048), bf16 out
  gemm256<0><<<dim3(16, 64), 512, 0, stream>>>(Ebf, Wkvt, KV, nullptr, 4096, 4);

  // pooled (into Ebf, no longer needed)
  winpool<<<dim3(L_SEQ / 4, HEADS), 256, 0, stream>>>(KV, q, Ebf);

  // out = pooled * Wo + bo   (M=16384, N=2048, K=2048), f32 out + bias
  gemm256<1><<<dim3(8, 64), 512, 0, stream>>>(Ebf, Wot, out, bo, 2048, 3);
}